// Round 6
// baseline (146.567 us; speedup 1.0000x reference)
//
#include <hip/hip_runtime.h>
#include <hip/hip_bf16.h>

// Problem: B=2, L=2048, D=1024, N=16  -> rows R = 4096, K = 1024
// y[r,d] = x[r,d] * softplus((x@W1^T)[r,d] + b1[d]) * s[r]
// s[r]   = sum_n (x@W2^T + b2)[r,n] * (x@W3^T + b3)[r,n]
// (dA * h0 == 0, so A is unused.)

#define ROWS 4096
#define KDIM 1024

typedef __attribute__((ext_vector_type(8))) __bf16 bf16x8;
typedef __attribute__((ext_vector_type(4))) float f32x4;

// ---------- helpers ----------
__device__ __forceinline__ unsigned short f2bf_rne(float f) {
    unsigned u = __float_as_uint(f);
    u += 0x7FFFu + ((u >> 16) & 1u);   // round-to-nearest-even
    return (unsigned short)(u >> 16);
}
__device__ __forceinline__ unsigned pack2(float lo, float hi) {
    return (unsigned)f2bf_rne(lo) | ((unsigned)f2bf_rne(hi) << 16);
}

// ---------- kernel 1: pure streaming fp32 -> bf16 (x, W1, W2, W3) ----------
// 2576 blocks x 256 thr x 8 elems = 5,275,648 elements exactly.
__global__ __launch_bounds__(256) void prep_kernel(
        const float* __restrict__ x,  const float* __restrict__ W1,
        const float* __restrict__ W2, const float* __restrict__ W3,
        unsigned short* __restrict__ xb, unsigned short* __restrict__ w1b,
        unsigned short* __restrict__ w2b, unsigned short* __restrict__ w3b) {
    const long long NX  = (long long)ROWS * KDIM;   // 4,194,304
    const long long NW1 = (long long)KDIM * KDIM;   // 1,048,576
    const long long NW  = 16LL * KDIM;              // 16,384
    long long i = ((long long)blockIdx.x * 256 + threadIdx.x) * 8;
    const float* src;
    unsigned short* dst;
    if (i < NX)                 { src = x  + i;                 dst = xb  + i; }
    else if (i < NX + NW1)      { src = W1 + (i - NX);          dst = w1b + (i - NX); }
    else if (i < NX + NW1 + NW) { src = W2 + (i - NX - NW1);    dst = w2b + (i - NX - NW1); }
    else                        { src = W3 + (i - NX - NW1 - NW); dst = w3b + (i - NX - NW1 - NW); }
    float4 a = *(const float4*)src;
    float4 b = *(const float4*)(src + 4);
    uint4 o;
    o.x = pack2(a.x, a.y); o.y = pack2(a.z, a.w);
    o.z = pack2(b.x, b.y); o.w = pack2(b.z, b.w);
    *(uint4*)dst = o;
}

// ---------- kernel 2: s[r] via MFMA over bf16 inputs (unchanged from R5) ----------
__global__ __launch_bounds__(256) void s_kernel(
        const unsigned short* __restrict__ xb,
        const unsigned short* __restrict__ w2b, const float* __restrict__ b2,
        const unsigned short* __restrict__ w3b, const float* __restrict__ b3,
        float* __restrict__ s) {
    __shared__ f32x4 redB[4][64];
    __shared__ f32x4 redC[4][64];
    const int t = threadIdx.x;
    const int lane = t & 63;
    const int wv = t >> 6;
    const int m = lane & 15;              // A row-within-16 / B n index
    const int kq = (lane >> 4) * 8;       // k offset within 32-step
    const int r0 = blockIdx.x * 16;
    const int kbase = wv * 256;

    f32x4 accB = (f32x4){0.f, 0.f, 0.f, 0.f};
    f32x4 accC = (f32x4){0.f, 0.f, 0.f, 0.f};
    const unsigned short* xr  = xb  + (size_t)(r0 + m) * KDIM + kbase + kq;
    const unsigned short* w2r = w2b + (size_t)m * KDIM + kbase + kq;
    const unsigned short* w3r = w3b + (size_t)m * KDIM + kbase + kq;
#pragma unroll
    for (int ks = 0; ks < 256; ks += 32) {
        bf16x8 af  = *(const bf16x8*)(xr  + ks);
        bf16x8 b2f = *(const bf16x8*)(w2r + ks);
        bf16x8 b3f = *(const bf16x8*)(w3r + ks);
        accB = __builtin_amdgcn_mfma_f32_16x16x32_bf16(af, b2f, accB, 0, 0, 0);
        accC = __builtin_amdgcn_mfma_f32_16x16x32_bf16(af, b3f, accC, 0, 0, 0);
    }
    redB[wv][lane] = accB;
    redC[wv][lane] = accC;
    __syncthreads();
    if (wv == 0) {
        f32x4 tB = redB[0][lane], tC = redC[0][lane];
#pragma unroll
        for (int w = 1; w < 4; ++w) { tB += redB[w][lane]; tC += redC[w][lane]; }
        // C/D layout: lane holds D[row=(lane>>4)*4+r][col = n = lane&15]
        const float b2n = b2[m], b3n = b3[m];
        const int q4 = (lane >> 4) * 4;
#pragma unroll
        for (int r = 0; r < 4; ++r) {
            float p = (tB[r] + b2n) * (tC[r] + b3n);
            p += __shfl_xor(p, 1, 64);
            p += __shfl_xor(p, 2, 64);
            p += __shfl_xor(p, 4, 64);
            p += __shfl_xor(p, 8, 64);
            if (m == 0) s[r0 + q4 + r] = p;
        }
    }
}

// ---------- kernel 3: LDS-free streaming MFMA GEMM + fused epilogue ----------
// v3: NO LDS, NO barriers. A/B fragments loaded directly from row-major bf16
// global memory (frag layout [m=lane&15][k=(lane>>4)*8+j] == contiguous 16 B
// per lane). Compiler is free to software-pipeline loads across MFMAs with
// fine-grained vmcnt (no s_barrier to force a vmcnt(0) drain -- the R5
// structure's stall). 512 blocks (XCD-swizzled: per-XCD working set = 1 MB
// xb strip + 2 MB w1b = L2-resident), 256 thr = 4 waves in 2x2; each wave
// 64x32 via 4x2 mfma_f32_16x16x32_bf16.
__global__ __launch_bounds__(256, 2) void gemm_fused(
        const unsigned short* __restrict__ xb,   // [4096][1024] bf16
        const unsigned short* __restrict__ w1b,  // [1024][1024] bf16 (row e, col k)
        const float* __restrict__ b1,
        const float* __restrict__ x,             // fp32 original
        const float* __restrict__ s,
        float* __restrict__ y) {
    const int bid = blockIdx.x;
    const int xcd = bid & 7;
    const int l = bid >> 3;                   // 0..63
    const int row0 = (xcd * 4 + (l >> 4)) * 128;
    const int col0 = (l & 15) * 64;

    const int t = threadIdx.x;
    const int lane = t & 63;
    const int wv = t >> 6;          // 0..3
    const int wm = wv >> 1;         // wave row 0..1 (64 rows each)
    const int wn = wv & 1;          // wave col 0..1 (32 cols each)
    const int m = lane & 15;
    const int kq = (lane >> 4) * 8;

    f32x4 acc[4][2];
#pragma unroll
    for (int mi = 0; mi < 4; ++mi)
#pragma unroll
        for (int ni = 0; ni < 2; ++ni)
            acc[mi][ni] = (f32x4){0.f, 0.f, 0.f, 0.f};

    // frag base pointers: A rows row0+wm*64+mi*16+m ; B rows col0+wn*32+ni*16+m
    const unsigned short* pa = xb  + (size_t)(row0 + wm * 64 + m) * KDIM + kq;
    const unsigned short* pb = w1b + (size_t)(col0 + wn * 32 + m) * KDIM + kq;

#pragma unroll 4
    for (int k0 = 0; k0 < KDIM; k0 += 32) {
        bf16x8 af[4], bfr[2];
#pragma unroll
        for (int i = 0; i < 4; ++i)
            af[i] = *(const bf16x8*)(pa + (size_t)i * 16 * KDIM + k0);
#pragma unroll
        for (int i = 0; i < 2; ++i)
            bfr[i] = *(const bf16x8*)(pb + (size_t)i * 16 * KDIM + k0);
#pragma unroll
        for (int mi = 0; mi < 4; ++mi)
#pragma unroll
            for (int ni = 0; ni < 2; ++ni)
                acc[mi][ni] = __builtin_amdgcn_mfma_f32_16x16x32_bf16(
                    af[mi], bfr[ni], acc[mi][ni], 0, 0, 0);
    }

    // epilogue: y = softplus(acc + b1) * x * s ; D layout: col=lane&15, row=(lane>>4)*4+reg
    const int q4 = (lane >> 4) * 4;
#pragma unroll
    for (int mi = 0; mi < 4; ++mi) {
        const int rbase = row0 + wm * 64 + mi * 16 + q4;
        float4 s4 = *(const float4*)&s[rbase];
        const float* sp4 = (const float*)&s4;
#pragma unroll
        for (int ni = 0; ni < 2; ++ni) {
            const int c = col0 + wn * 32 + ni * 16 + m;
            const float bias = b1[c];
#pragma unroll
            for (int r = 0; r < 4; ++r) {
                float z = acc[mi][ni][r] + bias;
                float sp = fmaxf(z, 0.f) + log1pf(__expf(-fabsf(z)));
                size_t idx = (size_t)(rbase + r) * KDIM + c;
                y[idx] = sp * x[idx] * sp4[r];
            }
        }
    }
}

// ---------- launch ----------
extern "C" void kernel_launch(void* const* d_in, const int* in_sizes, int n_in,
                              void* d_out, int out_size, void* d_ws, size_t ws_size,
                              hipStream_t stream) {
    const float* x  = (const float*)d_in[0];
    const float* W1 = (const float*)d_in[1];
    const float* b1 = (const float*)d_in[2];
    const float* W2 = (const float*)d_in[3];
    const float* b2 = (const float*)d_in[4];
    const float* W3 = (const float*)d_in[5];
    const float* b3 = (const float*)d_in[6];
    // d_in[7] = A : unused (multiplied by h0 == 0 in the reference)
    float* y = (float*)d_out;

    unsigned short* xb  = (unsigned short*)d_ws;              // 4096*1024 bf16 = 8 MB
    unsigned short* w1b = xb  + (size_t)ROWS * KDIM;          // 1024*1024 bf16 = 2 MB
    unsigned short* w2b = w1b + (size_t)KDIM * KDIM;          // 16*1024 bf16 = 32 KB
    unsigned short* w3b = w2b + (size_t)16 * KDIM;            // 16*1024 bf16 = 32 KB
    float* s = (float*)(w3b + (size_t)16 * KDIM);             // 4096 f32

    prep_kernel<<<dim3(2576), dim3(256), 0, stream>>>(x, W1, W2, W3, xb, w1b, w2b, w3b);
    s_kernel<<<dim3(256), dim3(256), 0, stream>>>(xb, w2b, b2, w3b, b3, s);
    gemm_fused<<<dim3(512), dim3(256), 0, stream>>>(xb, w1b, b1, x, s, y);
}